// Round 2
// baseline (384.178 us; speedup 1.0000x reference)
//
#include <hip/hip_runtime.h>
#include <hip/hip_bf16.h>

#define B_SZ 4096
#define N_SZ 200
#define D_SZ 64

// workspace float offsets
#define OFF_W1T   0              // [64][64] w1T[d][k] = gu_w1[k][d]        (first half)
#define OFF_W2T   4096           // [64][64] w2T[d][k] = gu_w2[k][d]
#define OFF_AW1T  8192           // [64][64] aw1T[d][k] = att_w1[k][d]      (first half)
#define OFF_AW1BT 12288          // [64][64] aw1bT[d][k] = att_w1[k][64+d]  (second half)
#define OFF_ERC   16384          // [6][64]  erc[r][k] = gu_b1[k] + sum_d gu_w1[k][64+d]*rate_emb[r][d]
#define OFF_QC    16768          // [B][64]  qc[b][k] = sum_d att_w1[k][64+d]*item_emb[iids[b]][d]
#define OFF_AGG   (16768 + B_SZ*64)  // [B][64] aggregated (pre final GEMM)
// total = 541056 floats ~= 2.07 MiB of d_ws

__global__ void prep1(const float* __restrict__ gu_w1, const float* __restrict__ gu_b1,
                      const float* __restrict__ gu_w2, const float* __restrict__ att_w1,
                      const float* __restrict__ rate_emb, float* __restrict__ ws) {
    int t = threadIdx.x;  // 1 block x 256 threads
    for (int idx = t; idx < 4096; idx += 256) {
        int d = idx >> 6, k = idx & 63;
        ws[OFF_W1T + idx]   = gu_w1[k * 128 + d];
        ws[OFF_W2T + idx]   = gu_w2[k * 64 + d];
        ws[OFF_AW1T + idx]  = att_w1[k * 128 + d];
        ws[OFF_AW1BT + idx] = att_w1[k * 128 + 64 + d];
    }
    // BUG FIX (round 1): this was `if (t < 384)` under blockDim=256 — rows
    // r=4,5 of erc were never written (poison workspace read as layer-1 bias).
    for (int t2 = t; t2 < 384; t2 += 256) {
        int r = t2 >> 6, k = t2 & 63;
        float a = gu_b1[k];
        for (int d = 0; d < 64; ++d)
            a += gu_w1[k * 128 + 64 + d] * rate_emb[r * 64 + d];
        ws[OFF_ERC + t2] = a;
    }
}

// qc[b][k] = sum_d att_w1[k][64+d] * item_emb[iids[b]][d]
__global__ void prep2_qc(const int* __restrict__ iids, const float* __restrict__ item_emb,
                         const float* __restrict__ ws, float* __restrict__ qc) {
    int b = blockIdx.x, k = threadIdx.x;  // B blocks x 64 threads
    int iid = iids[b];
    const float* awbT = ws + OFF_AW1BT;
    const float* irow = item_emb + (size_t)iid * 64;
    float acc = 0.f;
    for (int d = 0; d < 64; ++d)
        acc = fmaf(awbT[d * 64 + k], irow[d], acc);  // irow[d] wave-uniform -> s_load
    qc[b * 64 + k] = acc;
}

__global__ __launch_bounds__(256, 2) void fused_main(
    const int* __restrict__ pad, const float* __restrict__ user_emb,
    const float* __restrict__ gu_b2, const float* __restrict__ att_b1,
    const float* __restrict__ att_w2, const float* __restrict__ att_b2,
    const float* __restrict__ ws, float* __restrict__ aggbuf) {
    __shared__ float buf[4][64 * 65];  // per-wave row buffer (x -> h -> f), pad 65
    __shared__ float er_s[6 * 65];
    __shared__ float miu_s[256];
    __shared__ float red_s[4];
    __shared__ float aggp[4][64];

    const int b = blockIdx.x;
    const int w = threadIdx.x >> 6, lane = threadIdx.x & 63;
    float* mybuf = buf[w];
    const float* w1T  = ws + OFF_W1T;
    const float* w2T  = ws + OFF_W2T;
    const float* aw1T = ws + OFF_AW1T;
    const float* erc  = ws + OFF_ERC;
    const float* qc   = ws + OFF_QC;

    // stage erc (tiny) into LDS with pad-65 rows
    for (int t = threadIdx.x; t < 384; t += 256) {
        int r = t >> 6, k = t & 63;
        er_s[r * 65 + k] = erc[t];
    }

    // stage p_t rows for this wave: rows n = 4*i + w, coalesced 256B per row
    const int base = b * N_SZ;
    for (int i = 0; i < 50; ++i) {
        int n = 4 * i + w;
        int uid = pad[(base + n) * 2];  // wave-uniform
        mybuf[i * 65 + lane] = user_emb[(size_t)uid * 64 + lane];
    }
    __syncthreads();  // er_s is cross-wave

    const int j = lane;
    const bool active = (j < 50);
    const int nj = 4 * j + w;                       // < 256
    const int idx2 = (base + (active ? nj : 0)) * 2;
    const int uid_j = pad[idx2];
    const int rid_j = pad[idx2 + 1];
    const float mask = (active && uid_j > 0) ? 1.f : 0.f;

    float acc[64];

    // ---- layer 1: h = relu(W1a @ p + erc[rid]) ----
#pragma unroll
    for (int k = 0; k < 64; ++k) acc[k] = er_s[rid_j * 65 + k];
    for (int d = 0; d < 64; ++d) {
        float xv = mybuf[j * 65 + d];
#pragma unroll
        for (int k = 0; k < 64; ++k) acc[k] = fmaf(w1T[d * 64 + k], xv, acc[k]);
    }
#pragma unroll
    for (int k = 0; k < 64; ++k) mybuf[j * 65 + k] = fmaxf(acc[k], 0.f);

    // ---- layer 2: f = W2 @ h + b2 ----
#pragma unroll
    for (int k = 0; k < 64; ++k) acc[k] = gu_b2[k];
    for (int d = 0; d < 64; ++d) {
        float hv = mybuf[j * 65 + d];
#pragma unroll
        for (int k = 0; k < 64; ++k) acc[k] = fmaf(w2T[d * 64 + k], hv, acc[k]);
    }
#pragma unroll
    for (int k = 0; k < 64; ++k) mybuf[j * 65 + k] = acc[k];  // f_jt lives in LDS

    // ---- layer 3: ah = relu(AW1a @ f + ab1 + mask*qc[b]); miu = ah . att_w2 + ab2 ----
#pragma unroll
    for (int k = 0; k < 64; ++k) acc[k] = att_b1[k] + mask * qc[b * 64 + k];
    for (int d = 0; d < 64; ++d) {
        float fv = mybuf[j * 65 + d];
#pragma unroll
        for (int k = 0; k < 64; ++k) acc[k] = fmaf(aw1T[d * 64 + k], fv, acc[k]);
    }
    float miu = att_b2[0];
#pragma unroll
    for (int k = 0; k < 64; ++k) miu = fmaf(fmaxf(acc[k], 0.f), att_w2[k], miu);

    float m = active ? expf(miu) * mask : 0.f;   // inactive lanes contribute 0
    miu_s[nj] = m;

    // block-wide sum of m
    float s = m;
#pragma unroll
    for (int o = 32; o > 0; o >>= 1) s += __shfl_down(s, o);
    if (lane == 0) red_s[w] = s;
    __syncthreads();
    const float inv = 1.f / (red_s[0] + red_s[1] + red_s[2] + red_s[3] + 1e-10f);

    // agg[k] partial over this wave's rows (f rows are in mybuf)
    float aggk = 0.f;
    for (int i = 0; i < 50; ++i)
        aggk = fmaf(miu_s[4 * i + w], mybuf[i * 65 + lane], aggk);
    aggp[w][lane] = aggk * inv;
    __syncthreads();
    if (threadIdx.x < 64) {
        float a = aggp[0][lane] + aggp[1][lane] + aggp[2][lane] + aggp[3][lane];
        aggbuf[b * 64 + lane] = a;
    }
}

// z[b][k] = relu(agg_b[k] + sum_d agg_w[k][d] * agg[b][d])
__global__ __launch_bounds__(256) void final_z(const float* __restrict__ aggbuf,
                                               const float* __restrict__ agg_w,
                                               const float* __restrict__ agg_b,
                                               float* __restrict__ out) {
    __shared__ float aws[64 * 65];
    int t = threadIdx.x;
    for (int idx = t; idx < 4096; idx += 256)
        aws[(idx >> 6) * 65 + (idx & 63)] = agg_w[idx];
    __syncthreads();
    int g = t >> 6, k = t & 63;
    for (int bi = 0; bi < 2; ++bi) {
        int b = blockIdx.x * 8 + g * 2 + bi;
        const float* arow = aggbuf + b * 64;  // wave-uniform -> s_load
        float acc = agg_b[k];
        for (int d = 0; d < 64; ++d)
            acc = fmaf(aws[k * 65 + d], arow[d], acc);
        out[b * 64 + k] = fmaxf(acc, 0.f);
    }
}

extern "C" void kernel_launch(void* const* d_in, const int* in_sizes, int n_in,
                              void* d_out, int out_size, void* d_ws, size_t ws_size,
                              hipStream_t stream) {
    const int*   iids     = (const int*)d_in[0];
    const int*   pad      = (const int*)d_in[1];
    const float* user_emb = (const float*)d_in[2];
    const float* item_emb = (const float*)d_in[3];
    const float* rate_emb = (const float*)d_in[4];
    const float* gu_w1    = (const float*)d_in[5];
    const float* gu_b1    = (const float*)d_in[6];
    const float* gu_w2    = (const float*)d_in[7];
    const float* gu_b2    = (const float*)d_in[8];
    const float* att_w1   = (const float*)d_in[9];
    const float* att_b1   = (const float*)d_in[10];
    const float* att_w2   = (const float*)d_in[11];
    const float* att_b2   = (const float*)d_in[12];
    const float* agg_w    = (const float*)d_in[13];
    const float* agg_b    = (const float*)d_in[14];
    float* ws  = (float*)d_ws;
    float* out = (float*)d_out;

    hipLaunchKernelGGL(prep1, dim3(1), dim3(256), 0, stream,
                       gu_w1, gu_b1, gu_w2, att_w1, rate_emb, ws);
    hipLaunchKernelGGL(prep2_qc, dim3(B_SZ), dim3(64), 0, stream,
                       iids, item_emb, ws, ws + OFF_QC);
    hipLaunchKernelGGL(fused_main, dim3(B_SZ), dim3(256), 0, stream,
                       pad, user_emb, gu_b2, att_b1, att_w2, att_b2, ws, ws + OFF_AGG);
    hipLaunchKernelGGL(final_z, dim3(B_SZ / 8), dim3(256), 0, stream,
                       ws + OFF_AGG, agg_w, agg_b, out);
}

// Round 3
// 212.433 us; speedup vs baseline: 1.8085x; 1.8085x over previous
//
#include <hip/hip_runtime.h>
#include <hip/hip_bf16.h>

#define B_SZ 4096
#define N_SZ 200

// workspace offsets (4-byte units)
#define OFF_BFRAG 0        // 12288 u32: B-fragments, 3 layers x 2kt x 4ct x 2(hi/lo) x 64 lanes x 4 u32
#define OFF_AW1BT 12288    // 4096 f32: aw1bT[d][k] = att_w1[k][64+d]  (for qc prep)
#define OFF_ERC   16384    // 384  f32: erc[r][k] = gu_b1[k] + sum_d gu_w1[k][64+d]*rate_emb[r][d]
#define OFF_QC    16768    // B*64 f32: qc[b][k] = sum_d att_w1[k][64+d]*item_emb[iids[b]][d]

typedef __attribute__((ext_vector_type(8))) __bf16 bf16x8;
typedef __attribute__((ext_vector_type(4))) float f32x4;
typedef __attribute__((ext_vector_type(4))) unsigned u32x4;

// split f32 into bf16 hi + bf16 lo (RNE both), x ~= hi + lo with ~2^-17 rel err
__device__ __host__ __forceinline__ void split2(float x, unsigned &hi, unsigned &lo) {
    unsigned u = __float_as_uint(x);
    hi = (u + 0x7FFFu + ((u >> 16) & 1u)) >> 16;
    float r = x - __uint_as_float(hi << 16);
    unsigned ul = __float_as_uint(r);
    lo = (ul + 0x7FFFu + ((ul >> 16) & 1u)) >> 16;
}

// ---------- prep: B-fragments (split bf16), aw1bT, erc ----------
__global__ void prep1(const float* __restrict__ gu_w1, const float* __restrict__ gu_b1,
                      const float* __restrict__ gu_w2, const float* __restrict__ att_w1,
                      const float* __restrict__ rate_emb, float* __restrict__ ws) {
    int t = threadIdx.x;  // 1 block x 256
    unsigned* wsu = (unsigned*)ws;
    // B-fragment tables: frag f: hl=f&1, ct=(f>>1)&3, kt=(f>>3)&1, layer=f>>4
    // element: B[d][col] = W[col][d]; lane holds col=lane%16, d = kt*32+8*(lane/16)+e, e=2r,2r+1
    for (int i = t; i < 12288; i += 256) {
        int frag = i >> 8, within = i & 255, lane = within >> 2, r = within & 3;
        int hl = frag & 1, ct = (frag >> 1) & 3, kt = (frag >> 3) & 1, layer = frag >> 4;
        int col = ct * 16 + (lane & 15);
        int d0 = kt * 32 + 8 * (lane >> 4) + 2 * r;
        float w0, w1v;
        if (layer == 0)      { w0 = gu_w1[col * 128 + d0];  w1v = gu_w1[col * 128 + d0 + 1]; }
        else if (layer == 1) { w0 = gu_w2[col * 64 + d0];   w1v = gu_w2[col * 64 + d0 + 1]; }
        else                 { w0 = att_w1[col * 128 + d0]; w1v = att_w1[col * 128 + d0 + 1]; }
        unsigned h0, l0, h1, l1;
        split2(w0, h0, l0); split2(w1v, h1, l1);
        unsigned lo16 = hl ? l0 : h0;
        unsigned hi16 = hl ? l1 : h1;
        wsu[OFF_BFRAG + i] = lo16 | (hi16 << 16);
    }
    for (int i = t; i < 4096; i += 256) {
        int d = i >> 6, k = i & 63;
        ws[OFF_AW1BT + i] = att_w1[k * 128 + 64 + d];
    }
    for (int i = t; i < 384; i += 256) {
        int rr = i >> 6, k = i & 63;
        float a = gu_b1[k];
        for (int d = 0; d < 64; ++d)
            a += gu_w1[k * 128 + 64 + d] * rate_emb[rr * 64 + d];
        ws[OFF_ERC + i] = a;
    }
}

// qc[b][k] = sum_d att_w1[k][64+d] * item_emb[iids[b]][d]   (f32)
__global__ void prep2_qc(const int* __restrict__ iids, const float* __restrict__ item_emb,
                         const float* __restrict__ ws, float* __restrict__ qc) {
    int b = blockIdx.x, k = threadIdx.x;  // B blocks x 64 threads
    int iid = iids[b];
    const float* awbT = ws + OFF_AW1BT;
    const float* irow = item_emb + (size_t)iid * 64;
    float acc = 0.f;
    for (int d = 0; d < 64; ++d)
        acc = fmaf(awbT[d * 64 + k], irow[d], acc);
    qc[b * 64 + k] = acc;
}

// ---------- fused main: 3 MFMA layers + softmax + agg + final GEMM ----------
__global__ __launch_bounds__(256, 2) void fused_main(
    const int* __restrict__ pad, const float* __restrict__ user_emb,
    const float* __restrict__ gu_b2, const float* __restrict__ att_b1,
    const float* __restrict__ att_w2, const float* __restrict__ att_b2,
    const float* __restrict__ agg_w, const float* __restrict__ agg_b,
    const float* __restrict__ ws, float* __restrict__ out) {

    // X: 208 rows x 64 cols, u32 per element = (lo_bf16<<16)|hi_bf16.
    // 16B granule g of row n stored at granule (g ^ ((n&7)<<1)) to kill bank conflicts.
    __shared__ __align__(16) unsigned Xs[208 * 64];
    __shared__ float erc_s[6 * 65];
    __shared__ int   rid_s[208];
    __shared__ float mask_s[208];
    __shared__ float miu_s[208];
    __shared__ float b2_s[64], aw2_s[64], ab1_s[64], qc_s[64];
    __shared__ float aggp[4][64];
    __shared__ float agg_s[64];
    __shared__ float red_s[4];

    const int b = blockIdx.x;
    const int tid = threadIdx.x;
    const int w = tid >> 6;
    const int lane = tid & 63;
    const int lrow = lane & 15;    // A-operand row within 16-tile
    const int lgrp = lane >> 4;    // quarter-wave group
    const int lcol = lane & 15;    // C/D col within tile
    const unsigned* __restrict__ bfrag = (const unsigned*)ws + OFF_BFRAG;
    const float ab2 = att_b2[0];

    // ---- stage: gather user_emb rows, split to bf16 hi/lo, swizzled LDS ----
    {
        const int dq = tid & 15;               // 4-col group within row
        for (int p = 0; p < 13; ++p) {
            int n = p * 16 + (tid >> 4);
            int uid = 0, rid = 0;
            float4 v = make_float4(0.f, 0.f, 0.f, 0.f);
            if (n < N_SZ) {
                int2 pr = ((const int2*)pad)[b * N_SZ + n];
                uid = pr.x; rid = pr.y;
                v = *(const float4*)(user_emb + (size_t)uid * 64 + dq * 4);
            }
            unsigned h0, l0, h1, l1, h2, l2, h3, l3;
            split2(v.x, h0, l0); split2(v.y, h1, l1);
            split2(v.z, h2, l2); split2(v.w, h3, l3);
            u32x4 pk = { (l0 << 16) | h0, (l1 << 16) | h1, (l2 << 16) | h2, (l3 << 16) | h3 };
            int gp = dq ^ ((n & 7) << 1);
            *(u32x4*)&Xs[n * 64 + gp * 4] = pk;
            if (dq == 0) {
                rid_s[n]  = (n < N_SZ) ? rid : 0;
                mask_s[n] = (n < N_SZ && uid > 0) ? 1.f : 0.f;
            }
        }
        if (tid < 64) {
            b2_s[tid]  = gu_b2[tid];
            aw2_s[tid] = att_w2[tid];
            ab1_s[tid] = att_b1[tid];
            qc_s[tid]  = ws[OFF_QC + b * 64 + tid];
        }
        for (int i = tid; i < 384; i += 256)
            erc_s[(i >> 6) * 65 + (i & 63)] = ws[OFF_ERC + i];
    }
    __syncthreads();

    // A-frag loader: row n = rt*16 + lane%16, k = kt*32 + 8*(lane/16) + e (e=0..7)
    auto loadA = [&](int rt, int kt, bf16x8 &Ahi, bf16x8 &Alo) {
        int n = rt * 16 + lrow;
        int s = (n & 7) << 1;
        int g0 = kt * 8 + 2 * lgrp;
        u32x4 qa = *(const u32x4*)&Xs[n * 64 + ((g0 ^ s) << 2)];
        u32x4 qb = *(const u32x4*)&Xs[n * 64 + (((g0 + 1) ^ s) << 2)];
        u32x4 hh = { (qa[0] & 0xFFFFu) | (qa[1] << 16), (qa[2] & 0xFFFFu) | (qa[3] << 16),
                     (qb[0] & 0xFFFFu) | (qb[1] << 16), (qb[2] & 0xFFFFu) | (qb[3] << 16) };
        u32x4 ll = { (qa[0] >> 16) | (qa[1] & 0xFFFF0000u), (qa[2] >> 16) | (qa[3] & 0xFFFF0000u),
                     (qb[0] >> 16) | (qb[1] & 0xFFFF0000u), (qb[2] >> 16) | (qb[3] & 0xFFFF0000u) };
        Ahi = __builtin_bit_cast(bf16x8, hh);
        Alo = __builtin_bit_cast(bf16x8, ll);
    };

#define LOAD_B(LAYER)                                                            \
    u32x4 bh[4][2], bl[4][2];                                                    \
    _Pragma("unroll")                                                            \
    for (int ct = 0; ct < 4; ++ct)                                               \
        _Pragma("unroll")                                                        \
        for (int kt = 0; kt < 2; ++kt) {                                         \
            int fb = (((LAYER) * 2 + kt) * 4 + ct) * 2;                          \
            bh[ct][kt] = *(const u32x4*)&bfrag[(fb + 0) * 256 + lane * 4];       \
            bl[ct][kt] = *(const u32x4*)&bfrag[(fb + 1) * 256 + lane * 4];       \
        }

#define MFMA_ALL()                                                               \
    _Pragma("unroll")                                                            \
    for (int ct = 0; ct < 4; ++ct) {                                             \
        _Pragma("unroll")                                                        \
        for (int kt = 0; kt < 2; ++kt) {                                         \
            bf16x8 BH = __builtin_bit_cast(bf16x8, bh[ct][kt]);                  \
            bf16x8 BL = __builtin_bit_cast(bf16x8, bl[ct][kt]);                  \
            acc[ct] = __builtin_amdgcn_mfma_f32_16x16x32_bf16(Alo[kt], BH, acc[ct], 0, 0, 0); \
            acc[ct] = __builtin_amdgcn_mfma_f32_16x16x32_bf16(Ahi[kt], BL, acc[ct], 0, 0, 0); \
            acc[ct] = __builtin_amdgcn_mfma_f32_16x16x32_bf16(Ahi[kt], BH, acc[ct], 0, 0, 0); \
        }                                                                        \
    }

    // ---- layer 1: h = relu(P @ W1a^T + erc[rid])  (in-place into Xs) ----
    {
        LOAD_B(0)
        for (int rt = w; rt < 13; rt += 4) {
            bf16x8 Ahi[2], Alo[2];
            loadA(rt, 0, Ahi[0], Alo[0]);
            loadA(rt, 1, Ahi[1], Alo[1]);
            int nr[4], ridr[4];
#pragma unroll
            for (int r = 0; r < 4; ++r) { nr[r] = rt * 16 + lgrp * 4 + r; ridr[r] = rid_s[nr[r]]; }
            f32x4 acc[4];
#pragma unroll
            for (int ct = 0; ct < 4; ++ct) {
                int k = ct * 16 + lcol;
#pragma unroll
                for (int r = 0; r < 4; ++r) acc[ct][r] = erc_s[ridr[r] * 65 + k];
            }
            MFMA_ALL()
#pragma unroll
            for (int ct = 0; ct < 4; ++ct) {
                int k = ct * 16 + lcol;
#pragma unroll
                for (int r = 0; r < 4; ++r) {
                    float vv = fmaxf(acc[ct][r], 0.f);
                    unsigned hh, llv; split2(vv, hh, llv);
                    int n = nr[r];
                    Xs[n * 64 + ((((k >> 2) ^ ((n & 7) << 1)) << 2) | (k & 3))] = (llv << 16) | hh;
                }
            }
        }
    }

    // ---- layer 2: f = h @ W2^T + b2  (no relu; in-place into Xs) ----
    {
        LOAD_B(1)
        for (int rt = w; rt < 13; rt += 4) {
            bf16x8 Ahi[2], Alo[2];
            loadA(rt, 0, Ahi[0], Alo[0]);
            loadA(rt, 1, Ahi[1], Alo[1]);
            int nr[4];
#pragma unroll
            for (int r = 0; r < 4; ++r) nr[r] = rt * 16 + lgrp * 4 + r;
            f32x4 acc[4];
#pragma unroll
            for (int ct = 0; ct < 4; ++ct) {
                float bb = b2_s[ct * 16 + lcol];
#pragma unroll
                for (int r = 0; r < 4; ++r) acc[ct][r] = bb;
            }
            MFMA_ALL()
#pragma unroll
            for (int ct = 0; ct < 4; ++ct) {
                int k = ct * 16 + lcol;
#pragma unroll
                for (int r = 0; r < 4; ++r) {
                    unsigned hh, llv; split2(acc[ct][r], hh, llv);
                    int n = nr[r];
                    Xs[n * 64 + ((((k >> 2) ^ ((n & 7) << 1)) << 2) | (k & 3))] = (llv << 16) | hh;
                }
            }
        }
    }

    // ---- layer 3: ah = relu(f @ AW1a^T + ab1 + mask*qc); miu = exp(ah.aw2 + ab2)*mask ----
    {
        LOAD_B(2)
        for (int rt = w; rt < 13; rt += 4) {
            bf16x8 Ahi[2], Alo[2];
            loadA(rt, 0, Ahi[0], Alo[0]);
            loadA(rt, 1, Ahi[1], Alo[1]);
            int nr[4]; float maskr[4];
#pragma unroll
            for (int r = 0; r < 4; ++r) { nr[r] = rt * 16 + lgrp * 4 + r; maskr[r] = mask_s[nr[r]]; }
            f32x4 acc[4];
#pragma unroll
            for (int ct = 0; ct < 4; ++ct) {
                int k = ct * 16 + lcol;
                float bb = ab1_s[k], qq = qc_s[k];
#pragma unroll
                for (int r = 0; r < 4; ++r) acc[ct][r] = fmaf(maskr[r], qq, bb);
            }
            MFMA_ALL()
            float pm0 = 0.f, pm1 = 0.f, pm2 = 0.f, pm3 = 0.f;
#pragma unroll
            for (int ct = 0; ct < 4; ++ct) {
                float w2v = aw2_s[ct * 16 + lcol];
                pm0 = fmaf(fmaxf(acc[ct][0], 0.f), w2v, pm0);
                pm1 = fmaf(fmaxf(acc[ct][1], 0.f), w2v, pm1);
                pm2 = fmaf(fmaxf(acc[ct][2], 0.f), w2v, pm2);
                pm3 = fmaf(fmaxf(acc[ct][3], 0.f), w2v, pm3);
            }
#pragma unroll
            for (int off = 1; off <= 8; off <<= 1) {
                pm0 += __shfl_xor(pm0, off);
                pm1 += __shfl_xor(pm1, off);
                pm2 += __shfl_xor(pm2, off);
                pm3 += __shfl_xor(pm3, off);
            }
            if (lcol < 4) {
                float pv = (lcol == 0) ? pm0 : (lcol == 1) ? pm1 : (lcol == 2) ? pm2 : pm3;
                int n = rt * 16 + lgrp * 4 + lcol;
                miu_s[n] = expf(pv + ab2) * mask_s[n];
            }
        }
    }
    __syncthreads();

    // ---- softmax denominator ----
    float sv = (tid < 208) ? miu_s[tid] : 0.f;
#pragma unroll
    for (int off = 32; off >= 1; off >>= 1) sv += __shfl_down(sv, off);
    if (lane == 0) red_s[w] = sv;
    __syncthreads();
    const float inv = 1.f / (red_s[0] + red_s[1] + red_s[2] + red_s[3] + 1e-10f);

    // ---- agg[k] = inv * sum_n miu[n] * f[n][k]  (f = hi+lo from Xs) ----
    {
        const int k = tid & 63, q = tid >> 6;
        const int gk = k >> 2, kb = k & 3;
        float a0 = 0.f, a1 = 0.f;
        for (int i = 0; i < 52; i += 2) {
            int n0 = q * 52 + i, n1 = n0 + 1;
            unsigned p0 = Xs[n0 * 64 + (((gk ^ ((n0 & 7) << 1)) << 2) | kb)];
            unsigned p1 = Xs[n1 * 64 + (((gk ^ ((n1 & 7) << 1)) << 2) | kb)];
            float m0 = miu_s[n0], m1 = miu_s[n1];
            a0 = fmaf(m0, __uint_as_float(p0 << 16), fmaf(m0, __uint_as_float(p0 & 0xFFFF0000u), a0));
            a1 = fmaf(m1, __uint_as_float(p1 << 16), fmaf(m1, __uint_as_float(p1 & 0xFFFF0000u), a1));
        }
        aggp[q][k] = a0 + a1;
    }
    __syncthreads();
    if (tid < 64)
        agg_s[tid] = (aggp[0][tid] + aggp[1][tid] + aggp[2][tid] + aggp[3][tid]) * inv;
    __syncthreads();

    // ---- z = relu(agg @ agg_w^T + agg_b) ----
    if (tid < 64) {
        const int k = tid;
        float z = agg_b[k];
        const float4* wr = (const float4*)(agg_w + k * 64);
#pragma unroll
        for (int i = 0; i < 16; ++i) {
            float4 wv = wr[i];
            z = fmaf(wv.x, agg_s[4 * i + 0], z);
            z = fmaf(wv.y, agg_s[4 * i + 1], z);
            z = fmaf(wv.z, agg_s[4 * i + 2], z);
            z = fmaf(wv.w, agg_s[4 * i + 3], z);
        }
        out[b * 64 + k] = fmaxf(z, 0.f);
    }
}

extern "C" void kernel_launch(void* const* d_in, const int* in_sizes, int n_in,
                              void* d_out, int out_size, void* d_ws, size_t ws_size,
                              hipStream_t stream) {
    const int*   iids     = (const int*)d_in[0];
    const int*   pad      = (const int*)d_in[1];
    const float* user_emb = (const float*)d_in[2];
    const float* item_emb = (const float*)d_in[3];
    const float* rate_emb = (const float*)d_in[4];
    const float* gu_w1    = (const float*)d_in[5];
    const float* gu_b1    = (const float*)d_in[6];
    const float* gu_w2    = (const float*)d_in[7];
    const float* gu_b2    = (const float*)d_in[8];
    const float* att_w1   = (const float*)d_in[9];
    const float* att_b1   = (const float*)d_in[10];
    const float* att_w2   = (const float*)d_in[11];
    const float* att_b2   = (const float*)d_in[12];
    const float* agg_w    = (const float*)d_in[13];
    const float* agg_b    = (const float*)d_in[14];
    float* ws  = (float*)d_ws;
    float* out = (float*)d_out;

    hipLaunchKernelGGL(prep1, dim3(1), dim3(256), 0, stream,
                       gu_w1, gu_b1, gu_w2, att_w1, rate_emb, ws);
    hipLaunchKernelGGL(prep2_qc, dim3(B_SZ), dim3(64), 0, stream,
                       iids, item_emb, ws, ws + OFF_QC);
    hipLaunchKernelGGL(fused_main, dim3(B_SZ), dim3(256), 0, stream,
                       pad, user_emb, gu_b2, att_b1, att_w2, att_b2, agg_w, agg_b, ws, out);
}

// Round 4
// 182.660 us; speedup vs baseline: 2.1032x; 1.1630x over previous
//
#include <hip/hip_runtime.h>
#include <hip/hip_bf16.h>

#define B_SZ 4096
#define N_SZ 200

// workspace offsets (4-byte units)
#define OFF_BFRAG 0        // 12288 u32: B-fragments, 3 layers x 2kt x 4ct x 2(hi/lo) x 64 lanes x 4 u32
#define OFF_AW1BT 12288    // 4096 f32: aw1bT[d][k] = att_w1[k][64+d]  (for qc prep)
#define OFF_ERC   16384    // 384  f32: erc[r][k] = gu_b1[k] + sum_d gu_w1[k][64+d]*rate_emb[r][d]
#define OFF_QC    16768    // B*64 f32: qc[b][k]

typedef __attribute__((ext_vector_type(8))) __bf16 bf16x8;
typedef __attribute__((ext_vector_type(4))) __bf16 bf16x4;
typedef __attribute__((ext_vector_type(4))) float f32x4;
typedef __attribute__((ext_vector_type(4))) unsigned u32x4;

// host/prep-side split (bit-exact RNE, used only in prep kernels)
__device__ __forceinline__ void split2(float x, unsigned &hi, unsigned &lo) {
    unsigned u = __float_as_uint(x);
    hi = (u + 0x7FFFu + ((u >> 16) & 1u)) >> 16;
    float r = x - __uint_as_float(hi << 16);
    unsigned ul = __float_as_uint(r);
    lo = (ul + 0x7FFFu + ((ul >> 16) & 1u)) >> 16;
}

// ---------- prep: B-fragments (split bf16), aw1bT, erc ----------
__global__ void prep1(const float* __restrict__ gu_w1, const float* __restrict__ gu_b1,
                      const float* __restrict__ gu_w2, const float* __restrict__ att_w1,
                      const float* __restrict__ rate_emb, float* __restrict__ ws) {
    int t = threadIdx.x;  // 1 block x 256
    unsigned* wsu = (unsigned*)ws;
    // frag f: hl=f&1, ct=(f>>1)&3, kt=(f>>3)&1, layer=f>>4
    // B[d][col] = W[col][d]; lane holds col=lane%16, d = kt*32+8*(lane/16)+e
    for (int i = t; i < 12288; i += 256) {
        int frag = i >> 8, within = i & 255, lane = within >> 2, r = within & 3;
        int hl = frag & 1, ct = (frag >> 1) & 3, kt = (frag >> 3) & 1, layer = frag >> 4;
        int col = ct * 16 + (lane & 15);
        int d0 = kt * 32 + 8 * (lane >> 4) + 2 * r;
        float w0, w1v;
        if (layer == 0)      { w0 = gu_w1[col * 128 + d0];  w1v = gu_w1[col * 128 + d0 + 1]; }
        else if (layer == 1) { w0 = gu_w2[col * 64 + d0];   w1v = gu_w2[col * 64 + d0 + 1]; }
        else                 { w0 = att_w1[col * 128 + d0]; w1v = att_w1[col * 128 + d0 + 1]; }
        unsigned h0, l0, h1, l1;
        split2(w0, h0, l0); split2(w1v, h1, l1);
        unsigned lo16 = hl ? l0 : h0;
        unsigned hi16 = hl ? l1 : h1;
        wsu[OFF_BFRAG + i] = lo16 | (hi16 << 16);
    }
    for (int i = t; i < 4096; i += 256) {
        int d = i >> 6, k = i & 63;
        ws[OFF_AW1BT + i] = att_w1[k * 128 + 64 + d];
    }
    for (int i = t; i < 384; i += 256) {
        int rr = i >> 6, k = i & 63;
        float a = gu_b1[k];
        for (int d = 0; d < 64; ++d)
            a += gu_w1[k * 128 + 64 + d] * rate_emb[rr * 64 + d];
        ws[OFF_ERC + i] = a;
    }
}

__global__ void prep2_qc(const int* __restrict__ iids, const float* __restrict__ item_emb,
                         const float* __restrict__ ws, float* __restrict__ qc) {
    int b = blockIdx.x, k = threadIdx.x;  // B blocks x 64 threads
    int iid = iids[b];
    const float* awbT = ws + OFF_AW1BT;
    const float* irow = item_emb + (size_t)iid * 64;
    float acc = 0.f;
    for (int d = 0; d < 64; ++d)
        acc = fmaf(awbT[d * 64 + k], irow[d], acc);
    qc[b * 64 + k] = acc;
}

// ---------- fused main ----------
__global__ __launch_bounds__(256, 2) void fused_main(
    const int* __restrict__ pad, const float* __restrict__ user_emb,
    const float* __restrict__ gu_b2, const float* __restrict__ att_b1,
    const float* __restrict__ att_w2, const float* __restrict__ att_b2,
    const float* __restrict__ agg_w, const float* __restrict__ agg_b,
    const float* __restrict__ ws, float* __restrict__ out) {

    // hi/lo activation planes: 208 rows x 64 cols bf16.
    // 16B granule g (8 cols) of row n stored at granule (g ^ (n&7)).
    __shared__ __align__(16) __bf16 XH[208 * 64];
    __shared__ __align__(16) __bf16 XL[208 * 64];
    __shared__ float erc_s[6 * 65];
    __shared__ int   rid_s[208];
    __shared__ float mask_s[208];
    __shared__ float b2_s[64], aw2_s[64], ab1_s[64], qc_s[64];
    __shared__ float aggp[4][64];
    __shared__ float agg_s[64];
    __shared__ float red_s[4];

    const int b = blockIdx.x;
    const int tid = threadIdx.x;
    const int w = tid >> 6;
    const int lane = tid & 63;
    const int lrow = lane & 15;
    const int lgrp = lane >> 4;
    const int lcol = lane & 15;
    const unsigned* __restrict__ bfrag = (const unsigned*)ws + OFF_BFRAG;
    const float ab2 = att_b2[0];

    // ---- stage: gather user_emb rows, hw-cvt split to hi/lo planes ----
    {
        const int dq = tid & 15;       // 4-col group
        const int rowt = tid >> 4;     // 0..15
        for (int p = 0; p < 13; ++p) {
            int n = p * 16 + rowt;
            int uid = 0, rid = 0;
            float4 v = make_float4(0.f, 0.f, 0.f, 0.f);
            if (n < N_SZ) {
                int2 pr = ((const int2*)pad)[b * N_SZ + n];
                uid = pr.x; rid = pr.y;
                v = *(const float4*)(user_emb + (size_t)uid * 64 + dq * 4);
            }
            __bf16 h0 = (__bf16)v.x, h1 = (__bf16)v.y, h2 = (__bf16)v.z, h3 = (__bf16)v.w;
            bf16x4 hv = { h0, h1, h2, h3 };
            bf16x4 lv = { (__bf16)(v.x - (float)h0), (__bf16)(v.y - (float)h1),
                          (__bf16)(v.z - (float)h2), (__bf16)(v.w - (float)h3) };
            int g = dq >> 1;
            int idx = n * 64 + ((g ^ (n & 7)) << 3) + (dq & 1) * 4;
            *(bf16x4*)&XH[idx] = hv;
            *(bf16x4*)&XL[idx] = lv;
            if (dq == 0) {
                rid_s[n]  = (n < N_SZ) ? rid : 0;
                mask_s[n] = (n < N_SZ && uid > 0) ? 1.f : 0.f;
            }
        }
        if (tid < 64) {
            b2_s[tid]  = gu_b2[tid];
            aw2_s[tid] = att_w2[tid];
            ab1_s[tid] = att_b1[tid];
            qc_s[tid]  = ws[OFF_QC + b * 64 + tid];
        }
        for (int i = tid; i < 384; i += 256)
            erc_s[(i >> 6) * 65 + (i & 63)] = ws[OFF_ERC + i];
    }
    __syncthreads();

    // A-frag: row n = rt*16+lrow, k = kt*32+8*lgrp+e  ->  exactly one swizzled granule
    auto loadA = [&](const __bf16* P, int rt, bf16x8 A[2]) {
        int n = rt * 16 + lrow;
        int s = n & 7;
#pragma unroll
        for (int kt = 0; kt < 2; ++kt)
            A[kt] = *(const bf16x8*)&P[n * 64 + (((kt * 4 + lgrp) ^ s) << 3)];
    };

#define LOAD_B(LAYER)                                                            \
    u32x4 bh[4][2], bl[4][2];                                                    \
    _Pragma("unroll")                                                            \
    for (int ct = 0; ct < 4; ++ct)                                               \
        _Pragma("unroll")                                                        \
        for (int kt = 0; kt < 2; ++kt) {                                         \
            int fb = (((LAYER) * 2 + kt) * 4 + ct) * 2;                          \
            bh[ct][kt] = *(const u32x4*)&bfrag[(fb + 0) * 256 + lane * 4];       \
            bl[ct][kt] = *(const u32x4*)&bfrag[(fb + 1) * 256 + lane * 4];       \
        }

#define MFMA3(ACC)                                                               \
    _Pragma("unroll")                                                            \
    for (int ct = 0; ct < 4; ++ct)                                               \
        _Pragma("unroll")                                                        \
        for (int kt = 0; kt < 2; ++kt) {                                         \
            bf16x8 BH = __builtin_bit_cast(bf16x8, bh[ct][kt]);                  \
            bf16x8 BL = __builtin_bit_cast(bf16x8, bl[ct][kt]);                  \
            ACC[ct] = __builtin_amdgcn_mfma_f32_16x16x32_bf16(AL[kt], BH, ACC[ct], 0, 0, 0); \
            ACC[ct] = __builtin_amdgcn_mfma_f32_16x16x32_bf16(AH[kt], BL, ACC[ct], 0, 0, 0); \
            ACC[ct] = __builtin_amdgcn_mfma_f32_16x16x32_bf16(AH[kt], BH, ACC[ct], 0, 0, 0); \
        }

#define MFMA2(ACC)                                                               \
    _Pragma("unroll")                                                            \
    for (int ct = 0; ct < 4; ++ct)                                               \
        _Pragma("unroll")                                                        \
        for (int kt = 0; kt < 2; ++kt) {                                         \
            bf16x8 BH = __builtin_bit_cast(bf16x8, bh[ct][kt]);                  \
            bf16x8 BL = __builtin_bit_cast(bf16x8, bl[ct][kt]);                  \
            ACC[ct] = __builtin_amdgcn_mfma_f32_16x16x32_bf16(AH[kt], BL, ACC[ct], 0, 0, 0); \
            ACC[ct] = __builtin_amdgcn_mfma_f32_16x16x32_bf16(AH[kt], BH, ACC[ct], 0, 0, 0); \
        }

    f32x4 f_reg[4][4];   // [tile t][ct] — layer-2 outputs, kept exact for agg

    // ---- layer 1: h = relu(P @ W1a^T + erc[rid]) ----
    {
        LOAD_B(0)
#pragma unroll
        for (int t = 0; t < 4; ++t) {
            int rt = w + 4 * t;
            if (rt < 13) {
                bf16x8 AH[2], AL[2];
                loadA(XH, rt, AH);
                loadA(XL, rt, AL);
                int nr[4], ridr[4];
#pragma unroll
                for (int r = 0; r < 4; ++r) { nr[r] = rt * 16 + lgrp * 4 + r; ridr[r] = rid_s[nr[r]]; }
                f32x4 acc[4];
#pragma unroll
                for (int ct = 0; ct < 4; ++ct) {
                    int k = ct * 16 + lcol;
#pragma unroll
                    for (int r = 0; r < 4; ++r) acc[ct][r] = erc_s[ridr[r] * 65 + k];
                }
                MFMA3(acc)
#pragma unroll
                for (int ct = 0; ct < 4; ++ct) {
                    int col = ct * 16 + lcol;
#pragma unroll
                    for (int r = 0; r < 4; ++r) {
                        float hv = fmaxf(acc[ct][r], 0.f);
                        __bf16 hh = (__bf16)hv;
                        __bf16 ll = (__bf16)(hv - (float)hh);
                        int n = nr[r];
                        int idx = n * 64 + ((((col >> 3)) ^ (n & 7)) << 3) + (col & 7);
                        XH[idx] = hh;
                        XL[idx] = ll;
                    }
                }
            }
        }
    }
    asm volatile("s_waitcnt lgkmcnt(0)" ::: "memory");
    __builtin_amdgcn_sched_barrier(0);

    // ---- layer 2: f = h @ W2^T + b2  (kept in regs; hi stored for layer 3) ----
    {
        LOAD_B(1)
#pragma unroll
        for (int t = 0; t < 4; ++t) {
            int rt = w + 4 * t;
            if (rt < 13) {
                bf16x8 AH[2], AL[2];
                loadA(XH, rt, AH);
                loadA(XL, rt, AL);
                f32x4 (&acc)[4] = f_reg[t];
#pragma unroll
                for (int ct = 0; ct < 4; ++ct) {
                    float bb = b2_s[ct * 16 + lcol];
#pragma unroll
                    for (int r = 0; r < 4; ++r) acc[ct][r] = bb;
                }
                MFMA3(acc)
#pragma unroll
                for (int ct = 0; ct < 4; ++ct) {
                    int col = ct * 16 + lcol;
#pragma unroll
                    for (int r = 0; r < 4; ++r) {
                        int n = rt * 16 + lgrp * 4 + r;
                        int idx = n * 64 + ((((col >> 3)) ^ (n & 7)) << 3) + (col & 7);
                        XH[idx] = (__bf16)acc[ct][r];   // hi only — layer-3 A operand
                    }
                }
            }
        }
    }
    asm volatile("s_waitcnt lgkmcnt(0)" ::: "memory");
    __builtin_amdgcn_sched_barrier(0);

    // ---- layer 3 + miu + in-register agg ----
    float aggr[4] = { 0.f, 0.f, 0.f, 0.f };
    float swave = 0.f;
    {
        LOAD_B(2)
#pragma unroll
        for (int t = 0; t < 4; ++t) {
            int rt = w + 4 * t;
            if (rt < 13) {
                bf16x8 AH[2];
                loadA(XH, rt, AH);
                float maskr[4];
                int nr[4];
#pragma unroll
                for (int r = 0; r < 4; ++r) { nr[r] = rt * 16 + lgrp * 4 + r; maskr[r] = mask_s[nr[r]]; }
                f32x4 acc[4];
#pragma unroll
                for (int ct = 0; ct < 4; ++ct) {
                    int k = ct * 16 + lcol;
                    float bb = ab1_s[k], qq = qc_s[k];
#pragma unroll
                    for (int r = 0; r < 4; ++r) acc[ct][r] = fmaf(maskr[r], qq, bb);
                }
                MFMA2(acc)
                float pm[4] = { 0.f, 0.f, 0.f, 0.f };
#pragma unroll
                for (int ct = 0; ct < 4; ++ct) {
                    float w2v = aw2_s[ct * 16 + lcol];
#pragma unroll
                    for (int r = 0; r < 4; ++r)
                        pm[r] = fmaf(fmaxf(acc[ct][r], 0.f), w2v, pm[r]);
                }
#pragma unroll
                for (int off = 1; off <= 8; off <<= 1) {
#pragma unroll
                    for (int r = 0; r < 4; ++r) pm[r] += __shfl_xor(pm[r], off);
                }
                // pm[r] now uniform within each 16-lane group == ah·w2 for row nr[r]
                float miur[4];
#pragma unroll
                for (int r = 0; r < 4; ++r) {
                    miur[r] = __expf(pm[r] + ab2) * maskr[r];
                    swave += miur[r];
                }
#pragma unroll
                for (int ct = 0; ct < 4; ++ct)
#pragma unroll
                    for (int r = 0; r < 4; ++r)
                        aggr[ct] = fmaf(miur[r], f_reg[t][ct][r], aggr[ct]);
            }
        }
    }
    // reduce partials across lane groups (values uniform within 16-lane group)
#pragma unroll
    for (int ct = 0; ct < 4; ++ct) {
        float v = aggr[ct];
        v += __shfl_xor(v, 16);
        v += __shfl_xor(v, 32);
        aggr[ct] = v;
    }
    swave += __shfl_xor(swave, 16);
    swave += __shfl_xor(swave, 32);
    if (lane < 16) {
#pragma unroll
        for (int ct = 0; ct < 4; ++ct) aggp[w][ct * 16 + lane] = aggr[ct];
    }
    if (lane == 0) red_s[w] = swave;
    __syncthreads();

    const float inv = 1.f / (red_s[0] + red_s[1] + red_s[2] + red_s[3] + 1e-10f);
    if (tid < 64)
        agg_s[tid] = (aggp[0][tid] + aggp[1][tid] + aggp[2][tid] + aggp[3][tid]) * inv;
    __syncthreads();

    // ---- z = relu(agg @ agg_w^T + agg_b) ----
    if (tid < 64) {
        const int k = tid;
        float z = agg_b[k];
        const float4* wr = (const float4*)(agg_w + k * 64);
#pragma unroll
        for (int i = 0; i < 16; ++i) {
            float4 wv = wr[i];
            z = fmaf(wv.x, agg_s[4 * i + 0], z);
            z = fmaf(wv.y, agg_s[4 * i + 1], z);
            z = fmaf(wv.z, agg_s[4 * i + 2], z);
            z = fmaf(wv.w, agg_s[4 * i + 3], z);
        }
        out[b * 64 + k] = fmaxf(z, 0.f);
    }
}

extern "C" void kernel_launch(void* const* d_in, const int* in_sizes, int n_in,
                              void* d_out, int out_size, void* d_ws, size_t ws_size,
                              hipStream_t stream) {
    const int*   iids     = (const int*)d_in[0];
    const int*   pad      = (const int*)d_in[1];
    const float* user_emb = (const float*)d_in[2];
    const float* item_emb = (const float*)d_in[3];
    const float* rate_emb = (const float*)d_in[4];
    const float* gu_w1    = (const float*)d_in[5];
    const float* gu_b1    = (const float*)d_in[6];
    const float* gu_w2    = (const float*)d_in[7];
    const float* gu_b2    = (const float*)d_in[8];
    const float* att_w1   = (const float*)d_in[9];
    const float* att_b1   = (const float*)d_in[10];
    const float* att_w2   = (const float*)d_in[11];
    const float* att_b2   = (const float*)d_in[12];
    const float* agg_w    = (const float*)d_in[13];
    const float* agg_b    = (const float*)d_in[14];
    float* ws  = (float*)d_ws;
    float* out = (float*)d_out;

    hipLaunchKernelGGL(prep1, dim3(1), dim3(256), 0, stream,
                       gu_w1, gu_b1, gu_w2, att_w1, rate_emb, ws);
    hipLaunchKernelGGL(prep2_qc, dim3(B_SZ), dim3(64), 0, stream,
                       iids, item_emb, ws, ws + OFF_QC);
    hipLaunchKernelGGL(fused_main, dim3(B_SZ), dim3(256), 0, stream,
                       pad, user_emb, gu_b2, att_b1, att_w2, att_b2, agg_w, agg_b, ws, out);
}